// Round 17
// baseline (553.804 us; speedup 1.0000x reference)
//
#include <hip/hip_runtime.h>
#include <hip/hip_bf16.h>
#include <math.h>

#define T_SEQ 2048
#define D_MODEL 1024
#define N_HEADS 16
#define HD 64
#define FF_DIM 4096
#define N_ROWS 4096   // b*t
#define LDQKV 3072

typedef __bf16 bf16x8 __attribute__((ext_vector_type(8)));
typedef float f32x4 __attribute__((ext_vector_type(4)));

__device__ __forceinline__ unsigned short f2bf(float f) {
  union { float f; unsigned u; } v; v.f = f;
  unsigned r = v.u + 0x7FFFu + ((v.u >> 16) & 1u);
  return (unsigned short)(r >> 16);
}
__device__ __forceinline__ float bf2f(unsigned short u) {
  union { unsigned u; float f; } v; v.u = ((unsigned)u) << 16;
  return v.f;
}
// hardware RNE f32-pair -> packed bf16 (low = a, high = b)
__device__ __forceinline__ unsigned cvtpk(float a, float b) {
  unsigned r;
  asm("v_cvt_pk_bf16_f32 %0, %1, %2" : "=v"(r) : "v"(a), "v"(b));
  return r;
}

__device__ __forceinline__ void gld_lds16(const void* g, void* l) {
  __builtin_amdgcn_global_load_lds(
      (const __attribute__((address_space(1))) unsigned int*)g,
      (__attribute__((address_space(3))) unsigned int*)l, 16, 0, 0);
}

// ---------- merged weight transpose: f32 [R][C] -> bf16 [C][R], 4 weights, 1 launch ----------
__global__ __launch_bounds__(256) void transpose_all(const float* __restrict__ wq,
                                                     const float* __restrict__ wo,
                                                     const float* __restrict__ w1,
                                                     const float* __restrict__ w2,
                                                     unsigned short* __restrict__ wqT,
                                                     unsigned short* __restrict__ woT,
                                                     unsigned short* __restrict__ w1T,
                                                     unsigned short* __restrict__ w2T) {
  int bid = blockIdx.x;
  const float* src; unsigned short* dst; int R, C, bx, by;
  if (bid < 3072)       { src = wq; dst = wqT; R = 1024; C = 3072; bx = bid % 96;  by = bid / 96; }
  else if (bid < 4096)  { int t = bid - 3072; src = wo; dst = woT; R = 1024; C = 1024; bx = t % 32;  by = t / 32; }
  else if (bid < 8192)  { int t = bid - 4096; src = w1; dst = w1T; R = 1024; C = 4096; bx = t % 128; by = t / 128; }
  else                  { int t = bid - 8192; src = w2; dst = w2T; R = 4096; C = 1024; bx = t % 32;  by = t / 32; }
  __shared__ float tile[32][33];
  int c0 = bx * 32, r0 = by * 32;
  int tx = threadIdx.x & 31, ty = threadIdx.x >> 5;  // ty 0..7
#pragma unroll
  for (int i = 0; i < 32; i += 8)
    tile[ty + i][tx] = src[(size_t)(r0 + ty + i) * C + c0 + tx];
  __syncthreads();
#pragma unroll
  for (int i = 0; i < 32; i += 8)
    dst[(size_t)(c0 + ty + i) * R + r0 + tx] = f2bf(tile[tx][ty + i]);
}

// ---------- layernorm: f32 row [1024] -> bf16 ----------
__global__ __launch_bounds__(256) void ln_kernel(const float* __restrict__ x,
                                                 const float* __restrict__ g,
                                                 const float* __restrict__ be,
                                                 unsigned short* __restrict__ out) {
  int row = blockIdx.x;
  float4 v = ((const float4*)(x + (size_t)row * D_MODEL))[threadIdx.x];
  float s = v.x + v.y + v.z + v.w;
  float ss = v.x * v.x + v.y * v.y + v.z * v.z + v.w * v.w;
#pragma unroll
  for (int o = 32; o; o >>= 1) { s += __shfl_down(s, o); ss += __shfl_down(ss, o); }
  __shared__ float red[8];
  int wid = threadIdx.x >> 6, lane = threadIdx.x & 63;
  if (lane == 0) { red[wid] = s; red[4 + wid] = ss; }
  __syncthreads();
  if (threadIdx.x == 0) {
    float S0 = red[0] + red[1] + red[2] + red[3];
    float S1 = red[4] + red[5] + red[6] + red[7];
    float m = S0 * (1.0f / D_MODEL);
    red[0] = m;
    red[1] = rsqrtf(S1 * (1.0f / D_MODEL) - m * m + 1e-5f);
  }
  __syncthreads();
  float m = red[0], inv = red[1];
  float4 gv = ((const float4*)g)[threadIdx.x];
  float4 bv = ((const float4*)be)[threadIdx.x];
  uint2 o;
  o.x = cvtpk((v.x - m) * inv * gv.x + bv.x, (v.y - m) * inv * gv.y + bv.y);
  o.y = cvtpk((v.z - m) * inv * gv.z + bv.z, (v.w - m) * inv * gv.w + bv.w);
  ((uint2*)(out + (size_t)row * D_MODEL))[threadIdx.x] = o;
}

// ---------- GEMM 128x128 (BK=32, DOUBLE-BUFFERED prefetch, XCD-chunked grid) ----------
// EPI 0 (qkv): cols<1024 -> qkvb (Q, x0.125); 1024..2047 -> kt panel; >=2048 -> vt2 tiled
// EPI 2 (ffn1): +bias, exact GELU, bf16
template <int EPI>
__global__ __launch_bounds__(256) void gemm_bt(const unsigned short* __restrict__ A,
                                               const unsigned short* __restrict__ Bt,
                                               int M, int N, int K,
                                               void* __restrict__ outp,
                                               const float* __restrict__ bias,
                                               unsigned short* __restrict__ ktp,
                                               unsigned short* __restrict__ vtp) {
  __shared__ __align__(16) unsigned short As[2][128 * 32];
  __shared__ __align__(16) unsigned short Bs[2][128 * 32];
  int tid = threadIdx.x;
  // XCD-chunked swizzle (T1): consecutive work (shared B-panels) -> same XCD.
  int nwg = gridDim.x * gridDim.y;              // divisible by 8 for all uses
  int lin = blockIdx.y * gridDim.x + blockIdx.x;
  lin = (lin & 7) * (nwg >> 3) + (lin >> 3);
  int m0 = (lin % gridDim.x) * 128, n0 = (lin / gridDim.x) * 128;
  int w = tid >> 6, l = tid & 63;
  int wm = w >> 1, wn = w & 1;
  int lr = l & 15, lg = l >> 4;
  f32x4 acc[4][4] = {};
  const unsigned short* ap0 = A + (size_t)(m0 + (tid >> 2)) * K + (tid & 3) * 8;
  const unsigned short* ap1 = ap0 + (size_t)64 * K;
  const unsigned short* bp0 = Bt + (size_t)(n0 + (tid >> 2)) * K + (tid & 3) * 8;
  const unsigned short* bp1 = bp0 + (size_t)64 * K;
  int ldso = (tid & ~63) * 8;
  auto stage = [&](int buf, int k0) {
    gld_lds16(ap0 + k0, &As[buf][ldso]);
    gld_lds16(ap1 + k0, &As[buf][2048 + ldso]);
    gld_lds16(bp0 + k0, &Bs[buf][ldso]);
    gld_lds16(bp1 + k0, &Bs[buf][2048 + ldso]);
  };
  int nt = K >> 5;
  stage(0, 0);
  __syncthreads();
  for (int t = 0; t < nt; t++) {
    int cur = t & 1;
    if (t + 1 < nt) stage(cur ^ 1, (t + 1) * 32);
    bf16x8 af[4], bfr[4];
#pragma unroll
    for (int i = 0; i < 4; i++) {
      af[i] = *(const bf16x8*)(&As[cur][(wm * 64 + i * 16 + lr) * 32 + lg * 8]);
      bfr[i] = *(const bf16x8*)(&Bs[cur][(wn * 64 + i * 16 + lr) * 32 + lg * 8]);
    }
#pragma unroll
    for (int i = 0; i < 4; i++)
#pragma unroll
      for (int j = 0; j < 4; j++)
        acc[i][j] = __builtin_amdgcn_mfma_f32_16x16x32_bf16(af[i], bfr[j], acc[i][j], 0, 0, 0);
    __syncthreads();
  }
#pragma unroll
  for (int i = 0; i < 4; i++) {
#pragma unroll
    for (int j = 0; j < 4; j++) {
      int col = n0 + wn * 64 + j * 16 + lr;
      int X = m0 + wm * 64 + i * 16 + lg * 4;   // rows X..X+3 (4-aligned, no wrap)
      if (EPI == 0) {
        if (col < 1024) {
#pragma unroll
          for (int r = 0; r < 4; r++)
            ((unsigned short*)outp)[(size_t)(X + r) * N + col] = f2bf(acc[i][j][r] * 0.125f);
        } else if (col < 2048) {
          int hk = (col - 1024) >> 6, d = col & 63;
          int bq = X >> 11, tq = X & 2047;
          unsigned short* kp = ktp + (((size_t)(bq * 16 + hk) << 11) + tq) * HD + d;
#pragma unroll
          for (int r = 0; r < 4; r++) kp[(size_t)r * HD] = f2bf(acc[i][j][r]);
        } else {
          int hv = (col - 2048) >> 6, d = col & 63;
          int bq = X >> 11, tq = X & 2047;
          unsigned short* vp = vtp + ((((size_t)(bq * 16 + hv) * 64 + (tq >> 5)) * HD + d) * 32 + (tq & 31));
          ushort4 o4;
          o4.x = f2bf(acc[i][j][0]); o4.y = f2bf(acc[i][j][1]);
          o4.z = f2bf(acc[i][j][2]); o4.w = f2bf(acc[i][j][3]);
          *(ushort4*)vp = o4;
        }
      } else {  // EPI == 2
#pragma unroll
        for (int r = 0; r < 4; r++) {
          float t2 = acc[i][j][r] + bias[col];
          ((unsigned short*)outp)[(size_t)(X + r) * N + col] =
              f2bf(0.5f * t2 * (1.0f + erff(t2 * 0.70710678f)));
        }
      }
    }
  }
}

// ---------- GEMM 64x128 (BK=64, T2-swizzled LDS, DOUBLE-BUFFERED, XCD-chunked) ----------
// EPI 1: f32 store, + res          (out-proj residual)
// EPI 3: +bias, +res, f32 store NT (ffn2 -> d_out, write-once output)
template <int EPI>
__global__ __launch_bounds__(256) void gemm_bt2(const unsigned short* __restrict__ A,
                                                const unsigned short* __restrict__ Bt,
                                                int M, int N, int K,
                                                void* __restrict__ outp,
                                                const float* __restrict__ bias,
                                                const float* __restrict__ res) {
  __shared__ __align__(16) unsigned short As[2][64 * 64];    // 16 KB
  __shared__ __align__(16) unsigned short Bs[2][128 * 64];   // 32 KB
  int tid = threadIdx.x;
  int nwg = gridDim.x * gridDim.y;
  int lin = blockIdx.y * gridDim.x + blockIdx.x;
  lin = (lin & 7) * (nwg >> 3) + (lin >> 3);
  int m0 = (lin % gridDim.x) * 64, n0 = (lin / gridDim.x) * 128;
  int w = tid >> 6, l = tid & 63;
  int lr = l & 15, lg = l >> 4;
  f32x4 acc[4][2] = {};
  int srow = tid >> 3;
  int scolb = ((tid & 7) * 16) ^ ((srow & 7) << 4);
  const unsigned short* apg = A + (size_t)(m0 + srow) * K + (scolb >> 1);
  const unsigned short* bpg = Bt + (size_t)(n0 + srow) * K + (scolb >> 1);
  auto stage = [&](int buf, int k0) {
    gld_lds16(apg + k0, &As[buf][tid * 8]);
    gld_lds16(apg + (size_t)32 * K + k0, &As[buf][2048 + tid * 8]);
    gld_lds16(bpg + k0, &Bs[buf][tid * 8]);
    gld_lds16(bpg + (size_t)32 * K + k0, &Bs[buf][2048 + tid * 8]);
    gld_lds16(bpg + (size_t)64 * K + k0, &Bs[buf][4096 + tid * 8]);
    gld_lds16(bpg + (size_t)96 * K + k0, &Bs[buf][6144 + tid * 8]);
  };
  int nt = K >> 6;
  stage(0, 0);
  __syncthreads();
  for (int t = 0; t < nt; t++) {
    int cur = t & 1;
    if (t + 1 < nt) stage(cur ^ 1, (t + 1) * 64);
#pragma unroll
    for (int kk = 0; kk < 2; kk++) {
      int cb = (lg * 16 + kk * 64) ^ ((lr & 7) << 4);
      bf16x8 af[4], bfr[2];
#pragma unroll
      for (int i = 0; i < 4; i++)
        af[i] = *(const bf16x8*)((const char*)As[cur] + (i * 16 + lr) * 128 + cb);
#pragma unroll
      for (int j = 0; j < 2; j++)
        bfr[j] = *(const bf16x8*)((const char*)Bs[cur] + (w * 32 + j * 16 + lr) * 128 + cb);
#pragma unroll
      for (int i = 0; i < 4; i++)
#pragma unroll
        for (int j = 0; j < 2; j++)
          acc[i][j] = __builtin_amdgcn_mfma_f32_16x16x32_bf16(af[i], bfr[j], acc[i][j], 0, 0, 0);
    }
    __syncthreads();
  }
#pragma unroll
  for (int i = 0; i < 4; i++) {
#pragma unroll
    for (int j = 0; j < 2; j++) {
      int col = n0 + w * 32 + j * 16 + lr;
#pragma unroll
      for (int r = 0; r < 4; r++) {
        int row = m0 + i * 16 + lg * 4 + r;
        size_t idx = (size_t)row * N + col;
        float v = acc[i][j][r];
        if (EPI == 1) {
          ((float*)outp)[idx] = res[idx] + v;
        } else {
          __builtin_nontemporal_store(v + bias[col] + res[idx], (float*)outp + idx);
        }
      }
    }
  }
}

// ---------- fused attention (R9-proven structure; attn_out stores NON-TEMPORAL) ----------
__global__ __launch_bounds__(512, 4) void attn_kernel(const unsigned short* __restrict__ qkv,
                                                      const unsigned short* __restrict__ kt,
                                                      const unsigned short* __restrict__ vt2,
                                                      const float* __restrict__ prev,
                                                      float* __restrict__ attn_out,
                                                      unsigned short* __restrict__ ctx) {
  __shared__ __align__(16) unsigned short S[16 * 2048];   // 65,536 B
  int bid = blockIdx.x;
  int nb = (bid & 7) * 512 + (bid >> 3);
  int bh = nb >> 7, rt = nb & 127;
  int b = bh >> 4, h = bh & 15;
  int r0 = rt * 16;
  int tid = threadIdx.x, w = tid >> 6, l = tid & 63;
  int lr = l & 15, lg = l >> 4;

  const unsigned short* qb = qkv + (size_t)(b * T_SEQ + r0 + lr) * LDQKV + h * HD + lg * 8;
  bf16x8 qf0 = *(const bf16x8*)(qb);          // Q pre-scaled by 1/8 in qkv epilogue
  bf16x8 qf1 = *(const bf16x8*)(qb + 32);

  // Phase 1 — QK^T: wave w owns key-cols [w*256, w*256+256); K from packed kt panel
  const unsigned short* kb0 = kt + (size_t)bh * T_SEQ * HD + lg * 8;
#pragma unroll
  for (int nt = 0; nt < 16; nt++) {
    int c = w * 256 + nt * 16 + lr;
    const unsigned short* kp = kb0 + (size_t)c * HD;
    bf16x8 kf0 = *(const bf16x8*)(kp);
    bf16x8 kf1 = *(const bf16x8*)(kp + 32);
    f32x4 a = {};
    __builtin_amdgcn_s_setprio(1);
    a = __builtin_amdgcn_mfma_f32_16x16x32_bf16(qf0, kf0, a, 0, 0, 0);
    a = __builtin_amdgcn_mfma_f32_16x16x32_bf16(qf1, kf1, a, 0, 0, 0);
    __builtin_amdgcn_s_setprio(0);
#pragma unroll
    for (int r = 0; r < 4; r++) {
      int row = lg * 4 + r;
      int byteoff = (c * 2) ^ ((row & 7) << 4);
      *(unsigned short*)((char*)S + row * 4096 + byteoff) = f2bf(a[r]);
    }
  }
  __syncthreads();

  // Phase 2 — softmax: wave w rows {2w, 2w+1}; prev coalesced float4
  const float* pvb = prev + ((size_t)bh * T_SEQ + r0 + 2 * w) * T_SEQ;
  float* arow0 = attn_out + ((size_t)bh * T_SEQ + r0 + 2 * w) * T_SEQ;
#pragma unroll
  for (int rr = 0; rr < 2; rr++) {
    int row = w * 2 + rr;
    char* Sr = (char*)S + row * 4096;
    int xv = (row & 7) << 4;
    const float* pr = pvb + (size_t)rr * T_SEQ;
    float* ar = arow0 + (size_t)rr * T_SEQ;
    f32x4 sv[8];
    float mx = -1e30f;
#pragma unroll
    for (int i = 0; i < 8; i++) {
      int c = l * 4 + i * 256;
      ushort4 sraw = *(const ushort4*)(Sr + ((2 * c) ^ xv));
      f32x4 p = *(const f32x4*)(pr + c);
      sv[i][0] = bf2f(sraw.x) + p[0];
      sv[i][1] = bf2f(sraw.y) + p[1];
      sv[i][2] = bf2f(sraw.z) + p[2];
      sv[i][3] = bf2f(sraw.w) + p[3];
      mx = fmaxf(mx, fmaxf(fmaxf(sv[i][0], sv[i][1]), fmaxf(sv[i][2], sv[i][3])));
    }
#pragma unroll
    for (int o = 32; o; o >>= 1) mx = fmaxf(mx, __shfl_xor(mx, o));
    float sum = 0.f;
#pragma unroll
    for (int i = 0; i < 8; i++) {
      sv[i][0] = __expf(sv[i][0] - mx);
      sv[i][1] = __expf(sv[i][1] - mx);
      sv[i][2] = __expf(sv[i][2] - mx);
      sv[i][3] = __expf(sv[i][3] - mx);
      sum += sv[i][0] + sv[i][1] + sv[i][2] + sv[i][3];
    }
#pragma unroll
    for (int o = 32; o; o >>= 1) sum += __shfl_xor(sum, o);
    float inv = 1.0f / sum;
#pragma unroll
    for (int i = 0; i < 8; i++) {
      int c = l * 4 + i * 256;
      f32x4 p4;
      p4[0] = sv[i][0] * inv; p4[1] = sv[i][1] * inv;
      p4[2] = sv[i][2] * inv; p4[3] = sv[i][3] * inv;
      __builtin_nontemporal_store(p4, (f32x4*)(ar + c));
      uint2 pk;
      pk.x = cvtpk(p4[0], p4[1]);
      pk.y = cvtpk(p4[2], p4[3]);
      *(uint2*)(Sr + ((2 * c) ^ xv)) = pk;
    }
  }
  __syncthreads();

  // Phase 3 — PV: wave w key-slice [w*256, +256); A = P (bf16 LDS), B = vt2 tiled
  f32x4 pacc[4] = {};
  const unsigned short* vb = vt2 + (size_t)bh * 64 * HD * 32;
#pragma unroll
  for (int kt_i = 0; kt_i < 8; kt_i++) {
    int kb = w * 256 + kt_i * 32;
    char* Sr = (char*)S + lr * 4096;
    int byteoff = ((kb + lg * 8) * 2) ^ ((lr & 7) << 4);
    bf16x8 af = *(const bf16x8*)(Sr + byteoff);
    const unsigned short* vtile = vb + (size_t)(kb >> 5) * HD * 32;
    __builtin_amdgcn_s_setprio(1);
#pragma unroll
    for (int nj = 0; nj < 4; nj++) {
      const unsigned short* vp = vtile + (size_t)(nj * 16 + lr) * 32 + lg * 8;
      bf16x8 bv = *(const bf16x8*)(vp);
      pacc[nj] = __builtin_amdgcn_mfma_f32_16x16x32_bf16(af, bv, pacc[nj], 0, 0, 0);
    }
    __builtin_amdgcn_s_setprio(0);
  }
  __syncthreads();

  float* P = (float*)S;
#pragma unroll
  for (int nj = 0; nj < 4; nj++)
#pragma unroll
    for (int r = 0; r < 4; r++)
      P[(w * 16 + lg * 4 + r) * 64 + nj * 16 + lr] = pacc[nj][r];
  __syncthreads();
  for (int e = tid; e < 1024; e += 512) {
    float s = 0.f;
#pragma unroll
    for (int ww = 0; ww < 8; ww++) s += P[ww * 1024 + e];
    int row = e >> 6, col = e & 63;
    ctx[(size_t)(b * T_SEQ + r0 + row) * D_MODEL + h * HD + col] = f2bf(s);
  }
}

extern "C" void kernel_launch(void* const* d_in, const int* in_sizes, int n_in,
                              void* d_out, int out_size, void* d_ws, size_t ws_size,
                              hipStream_t stream) {
  const float* x = (const float*)d_in[0];
  const float* prev = (const float*)d_in[1];
  const float* w_qkv = (const float*)d_in[2];
  const float* w_out = (const float*)d_in[3];
  const float* w1 = (const float*)d_in[4];
  const float* b1 = (const float*)d_in[5];
  const float* w2 = (const float*)d_in[6];
  const float* b2 = (const float*)d_in[7];
  const float* g1 = (const float*)d_in[8];
  const float* be1 = (const float*)d_in[9];
  const float* g2 = (const float*)d_in[10];
  const float* be2 = (const float*)d_in[11];
  float* out_x = (float*)d_out;
  float* out_attn = out_x + (size_t)N_ROWS * D_MODEL;

  char* p = (char*)d_ws;
  auto alloc = [&](size_t bytes) -> void* {
    void* r = (void*)p;
    p += (bytes + 255) & ~(size_t)255;
    return r;
  };
  unsigned short* wqkvT = (unsigned short*)alloc((size_t)3072 * 1024 * 2);
  unsigned short* woutT = (unsigned short*)alloc((size_t)1024 * 1024 * 2);
  unsigned short* w1T   = (unsigned short*)alloc((size_t)4096 * 1024 * 2);
  unsigned short* w2T   = (unsigned short*)alloc((size_t)1024 * 4096 * 2);
  unsigned short* ln1b  = (unsigned short*)alloc((size_t)N_ROWS * 1024 * 2);
  unsigned short* qkvb  = (unsigned short*)alloc((size_t)N_ROWS * 3072 * 2);
  unsigned short* ktb   = (unsigned short*)alloc((size_t)32 * 2048 * 64 * 2);
  unsigned short* vt2b  = (unsigned short*)alloc((size_t)32 * 64 * 64 * 32 * 2);
  unsigned short* ctxb  = (unsigned short*)alloc((size_t)N_ROWS * 1024 * 2);
  float*          x2b   = (float*)alloc((size_t)N_ROWS * 1024 * 4);
  unsigned short* ln2b  = (unsigned short*)alloc((size_t)N_ROWS * 1024 * 2);
  unsigned short* hb    = (unsigned short*)alloc((size_t)N_ROWS * 4096 * 2);

  transpose_all<<<12288, 256, 0, stream>>>(w_qkv, w_out, w1, w2, wqkvT, woutT, w1T, w2T);

  ln_kernel<<<N_ROWS, 256, 0, stream>>>(x, g1, be1, ln1b);
  gemm_bt<0><<<dim3(32, 24), 256, 0, stream>>>(ln1b, wqkvT, N_ROWS, 3072, 1024, qkvb, nullptr, ktb, vt2b);
  attn_kernel<<<32 * 128, 512, 0, stream>>>(qkvb, ktb, vt2b, prev, out_attn, ctxb);
  gemm_bt2<1><<<dim3(64, 8), 256, 0, stream>>>(ctxb, woutT, N_ROWS, 1024, 1024, x2b, nullptr, x);
  ln_kernel<<<N_ROWS, 256, 0, stream>>>(x2b, g2, be2, ln2b);
  gemm_bt<2><<<dim3(32, 32), 256, 0, stream>>>(ln2b, w1T, N_ROWS, 4096, 1024, hb, b1, nullptr, nullptr);
  gemm_bt2<3><<<dim3(64, 8), 256, 0, stream>>>(hb, w2T, N_ROWS, 1024, 4096, out_x, b2, x2b);
}

// Round 18
// 529.092 us; speedup vs baseline: 1.0467x; 1.0467x over previous
//
#include <hip/hip_runtime.h>
#include <hip/hip_bf16.h>
#include <math.h>

#define T_SEQ 2048
#define D_MODEL 1024
#define N_HEADS 16
#define HD 64
#define FF_DIM 4096
#define N_ROWS 4096   // b*t
#define LDQKV 3072

typedef __bf16 bf16x8 __attribute__((ext_vector_type(8)));
typedef float f32x4 __attribute__((ext_vector_type(4)));

__device__ __forceinline__ unsigned short f2bf(float f) {
  union { float f; unsigned u; } v; v.f = f;
  unsigned r = v.u + 0x7FFFu + ((v.u >> 16) & 1u);
  return (unsigned short)(r >> 16);
}
__device__ __forceinline__ float bf2f(unsigned short u) {
  union { unsigned u; float f; } v; v.u = ((unsigned)u) << 16;
  return v.f;
}
// hardware RNE f32-pair -> packed bf16 (low = a, high = b)
__device__ __forceinline__ unsigned cvtpk(float a, float b) {
  unsigned r;
  asm("v_cvt_pk_bf16_f32 %0, %1, %2" : "=v"(r) : "v"(a), "v"(b));
  return r;
}

__device__ __forceinline__ void gld_lds16(const void* g, void* l) {
  __builtin_amdgcn_global_load_lds(
      (const __attribute__((address_space(1))) unsigned int*)g,
      (__attribute__((address_space(3))) unsigned int*)l, 16, 0, 0);
}

// ---------- merged weight transpose: f32 [R][C] -> bf16 [C][R], 4 weights, 1 launch ----------
__global__ __launch_bounds__(256) void transpose_all(const float* __restrict__ wq,
                                                     const float* __restrict__ wo,
                                                     const float* __restrict__ w1,
                                                     const float* __restrict__ w2,
                                                     unsigned short* __restrict__ wqT,
                                                     unsigned short* __restrict__ woT,
                                                     unsigned short* __restrict__ w1T,
                                                     unsigned short* __restrict__ w2T) {
  int bid = blockIdx.x;
  const float* src; unsigned short* dst; int R, C, bx, by;
  if (bid < 3072)       { src = wq; dst = wqT; R = 1024; C = 3072; bx = bid % 96;  by = bid / 96; }
  else if (bid < 4096)  { int t = bid - 3072; src = wo; dst = woT; R = 1024; C = 1024; bx = t % 32;  by = t / 32; }
  else if (bid < 8192)  { int t = bid - 4096; src = w1; dst = w1T; R = 1024; C = 4096; bx = t % 128; by = t / 128; }
  else                  { int t = bid - 8192; src = w2; dst = w2T; R = 4096; C = 1024; bx = t % 32;  by = t / 32; }
  __shared__ float tile[32][33];
  int c0 = bx * 32, r0 = by * 32;
  int tx = threadIdx.x & 31, ty = threadIdx.x >> 5;  // ty 0..7
#pragma unroll
  for (int i = 0; i < 32; i += 8)
    tile[ty + i][tx] = src[(size_t)(r0 + ty + i) * C + c0 + tx];
  __syncthreads();
#pragma unroll
  for (int i = 0; i < 32; i += 8)
    dst[(size_t)(c0 + ty + i) * R + r0 + tx] = f2bf(tile[tx][ty + i]);
}

// ---------- layernorm: f32 row [1024] -> bf16 ----------
__global__ __launch_bounds__(256) void ln_kernel(const float* __restrict__ x,
                                                 const float* __restrict__ g,
                                                 const float* __restrict__ be,
                                                 unsigned short* __restrict__ out) {
  int row = blockIdx.x;
  float4 v = ((const float4*)(x + (size_t)row * D_MODEL))[threadIdx.x];
  float s = v.x + v.y + v.z + v.w;
  float ss = v.x * v.x + v.y * v.y + v.z * v.z + v.w * v.w;
#pragma unroll
  for (int o = 32; o; o >>= 1) { s += __shfl_down(s, o); ss += __shfl_down(ss, o); }
  __shared__ float red[8];
  int wid = threadIdx.x >> 6, lane = threadIdx.x & 63;
  if (lane == 0) { red[wid] = s; red[4 + wid] = ss; }
  __syncthreads();
  if (threadIdx.x == 0) {
    float S0 = red[0] + red[1] + red[2] + red[3];
    float S1 = red[4] + red[5] + red[6] + red[7];
    float m = S0 * (1.0f / D_MODEL);
    red[0] = m;
    red[1] = rsqrtf(S1 * (1.0f / D_MODEL) - m * m + 1e-5f);
  }
  __syncthreads();
  float m = red[0], inv = red[1];
  float4 gv = ((const float4*)g)[threadIdx.x];
  float4 bv = ((const float4*)be)[threadIdx.x];
  uint2 o;
  o.x = cvtpk((v.x - m) * inv * gv.x + bv.x, (v.y - m) * inv * gv.y + bv.y);
  o.y = cvtpk((v.z - m) * inv * gv.z + bv.z, (v.w - m) * inv * gv.w + bv.w);
  ((uint2*)(out + (size_t)row * D_MODEL))[threadIdx.x] = o;
}

// ---------- GEMM 128x128 (BK=32, DOUBLE-BUFFERED prefetch): A[M][K] x Bt[N][K] ----------
// EPI 0 (qkv): cols<1024 -> qkvb (Q, x0.125); 1024..2047 -> kt panel; >=2048 -> vt2 tiled
// EPI 2 (ffn1): +bias, exact GELU, bf16
template <int EPI>
__global__ __launch_bounds__(256) void gemm_bt(const unsigned short* __restrict__ A,
                                               const unsigned short* __restrict__ Bt,
                                               int M, int N, int K,
                                               void* __restrict__ outp,
                                               const float* __restrict__ bias,
                                               unsigned short* __restrict__ ktp,
                                               unsigned short* __restrict__ vtp) {
  __shared__ __align__(16) unsigned short As[2][128 * 32];
  __shared__ __align__(16) unsigned short Bs[2][128 * 32];
  int tid = threadIdx.x;
  int m0 = blockIdx.x * 128, n0 = blockIdx.y * 128;
  int w = tid >> 6, l = tid & 63;
  int wm = w >> 1, wn = w & 1;
  int lr = l & 15, lg = l >> 4;
  f32x4 acc[4][4] = {};
  const unsigned short* ap0 = A + (size_t)(m0 + (tid >> 2)) * K + (tid & 3) * 8;
  const unsigned short* ap1 = ap0 + (size_t)64 * K;
  const unsigned short* bp0 = Bt + (size_t)(n0 + (tid >> 2)) * K + (tid & 3) * 8;
  const unsigned short* bp1 = bp0 + (size_t)64 * K;
  int ldso = (tid & ~63) * 8;
  auto stage = [&](int buf, int k0) {
    gld_lds16(ap0 + k0, &As[buf][ldso]);
    gld_lds16(ap1 + k0, &As[buf][2048 + ldso]);
    gld_lds16(bp0 + k0, &Bs[buf][ldso]);
    gld_lds16(bp1 + k0, &Bs[buf][2048 + ldso]);
  };
  int nt = K >> 5;
  stage(0, 0);
  __syncthreads();
  for (int t = 0; t < nt; t++) {
    int cur = t & 1;
    if (t + 1 < nt) stage(cur ^ 1, (t + 1) * 32);
    bf16x8 af[4], bfr[4];
#pragma unroll
    for (int i = 0; i < 4; i++) {
      af[i] = *(const bf16x8*)(&As[cur][(wm * 64 + i * 16 + lr) * 32 + lg * 8]);
      bfr[i] = *(const bf16x8*)(&Bs[cur][(wn * 64 + i * 16 + lr) * 32 + lg * 8]);
    }
#pragma unroll
    for (int i = 0; i < 4; i++)
#pragma unroll
      for (int j = 0; j < 4; j++)
        acc[i][j] = __builtin_amdgcn_mfma_f32_16x16x32_bf16(af[i], bfr[j], acc[i][j], 0, 0, 0);
    __syncthreads();
  }
#pragma unroll
  for (int i = 0; i < 4; i++) {
#pragma unroll
    for (int j = 0; j < 4; j++) {
      int col = n0 + wn * 64 + j * 16 + lr;
      int X = m0 + wm * 64 + i * 16 + lg * 4;   // rows X..X+3 (4-aligned, no wrap)
      if (EPI == 0) {
        if (col < 1024) {
#pragma unroll
          for (int r = 0; r < 4; r++)
            ((unsigned short*)outp)[(size_t)(X + r) * N + col] = f2bf(acc[i][j][r] * 0.125f);
        } else if (col < 2048) {
          int hk = (col - 1024) >> 6, d = col & 63;
          int bq = X >> 11, tq = X & 2047;
          unsigned short* kp = ktp + (((size_t)(bq * 16 + hk) << 11) + tq) * HD + d;
#pragma unroll
          for (int r = 0; r < 4; r++) kp[(size_t)r * HD] = f2bf(acc[i][j][r]);
        } else {
          int hv = (col - 2048) >> 6, d = col & 63;
          int bq = X >> 11, tq = X & 2047;
          unsigned short* vp = vtp + ((((size_t)(bq * 16 + hv) * 64 + (tq >> 5)) * HD + d) * 32 + (tq & 31));
          ushort4 o4;
          o4.x = f2bf(acc[i][j][0]); o4.y = f2bf(acc[i][j][1]);
          o4.z = f2bf(acc[i][j][2]); o4.w = f2bf(acc[i][j][3]);
          *(ushort4*)vp = o4;
        }
      } else {  // EPI == 2
#pragma unroll
        for (int r = 0; r < 4; r++) {
          float t2 = acc[i][j][r] + bias[col];
          ((unsigned short*)outp)[(size_t)(X + r) * N + col] =
              f2bf(0.5f * t2 * (1.0f + erff(t2 * 0.70710678f)));
        }
      }
    }
  }
}

// ---------- GEMM 64x128 (BK=64, T2-swizzled LDS, DOUBLE-BUFFERED): N=1024 GEMMs ----------
// EPI 1: f32 store, + res          (out-proj residual)
// EPI 3: +bias, +res, f32 store NT (ffn2 -> d_out, write-once output)
template <int EPI>
__global__ __launch_bounds__(256) void gemm_bt2(const unsigned short* __restrict__ A,
                                                const unsigned short* __restrict__ Bt,
                                                int M, int N, int K,
                                                void* __restrict__ outp,
                                                const float* __restrict__ bias,
                                                const float* __restrict__ res) {
  __shared__ __align__(16) unsigned short As[2][64 * 64];    // 16 KB
  __shared__ __align__(16) unsigned short Bs[2][128 * 64];   // 32 KB
  int tid = threadIdx.x;
  int m0 = blockIdx.x * 64, n0 = blockIdx.y * 128;
  int w = tid >> 6, l = tid & 63;
  int lr = l & 15, lg = l >> 4;
  f32x4 acc[4][2] = {};
  int srow = tid >> 3;
  int scolb = ((tid & 7) * 16) ^ ((srow & 7) << 4);
  const unsigned short* apg = A + (size_t)(m0 + srow) * K + (scolb >> 1);
  const unsigned short* bpg = Bt + (size_t)(n0 + srow) * K + (scolb >> 1);
  auto stage = [&](int buf, int k0) {
    gld_lds16(apg + k0, &As[buf][tid * 8]);
    gld_lds16(apg + (size_t)32 * K + k0, &As[buf][2048 + tid * 8]);
    gld_lds16(bpg + k0, &Bs[buf][tid * 8]);
    gld_lds16(bpg + (size_t)32 * K + k0, &Bs[buf][2048 + tid * 8]);
    gld_lds16(bpg + (size_t)64 * K + k0, &Bs[buf][4096 + tid * 8]);
    gld_lds16(bpg + (size_t)96 * K + k0, &Bs[buf][6144 + tid * 8]);
  };
  int nt = K >> 6;
  stage(0, 0);
  __syncthreads();
  for (int t = 0; t < nt; t++) {
    int cur = t & 1;
    if (t + 1 < nt) stage(cur ^ 1, (t + 1) * 64);
#pragma unroll
    for (int kk = 0; kk < 2; kk++) {
      int cb = (lg * 16 + kk * 64) ^ ((lr & 7) << 4);
      bf16x8 af[4], bfr[2];
#pragma unroll
      for (int i = 0; i < 4; i++)
        af[i] = *(const bf16x8*)((const char*)As[cur] + (i * 16 + lr) * 128 + cb);
#pragma unroll
      for (int j = 0; j < 2; j++)
        bfr[j] = *(const bf16x8*)((const char*)Bs[cur] + (w * 32 + j * 16 + lr) * 128 + cb);
#pragma unroll
      for (int i = 0; i < 4; i++)
#pragma unroll
        for (int j = 0; j < 2; j++)
          acc[i][j] = __builtin_amdgcn_mfma_f32_16x16x32_bf16(af[i], bfr[j], acc[i][j], 0, 0, 0);
    }
    __syncthreads();
  }
#pragma unroll
  for (int i = 0; i < 4; i++) {
#pragma unroll
    for (int j = 0; j < 2; j++) {
      int col = n0 + w * 32 + j * 16 + lr;
#pragma unroll
      for (int r = 0; r < 4; r++) {
        int row = m0 + i * 16 + lg * 4 + r;
        size_t idx = (size_t)row * N + col;
        float v = acc[i][j][r];
        if (EPI == 1) {
          ((float*)outp)[idx] = res[idx] + v;
        } else {
          __builtin_nontemporal_store(v + bias[col] + res[idx], (float*)outp + idx);
        }
      }
    }
  }
}

// ---------- fused attention (R9-proven structure; attn_out stores NON-TEMPORAL) ----------
__global__ __launch_bounds__(512, 4) void attn_kernel(const unsigned short* __restrict__ qkv,
                                                      const unsigned short* __restrict__ kt,
                                                      const unsigned short* __restrict__ vt2,
                                                      const float* __restrict__ prev,
                                                      float* __restrict__ attn_out,
                                                      unsigned short* __restrict__ ctx) {
  __shared__ __align__(16) unsigned short S[16 * 2048];   // 65,536 B
  int bid = blockIdx.x;
  int nb = (bid & 7) * 512 + (bid >> 3);
  int bh = nb >> 7, rt = nb & 127;
  int b = bh >> 4, h = bh & 15;
  int r0 = rt * 16;
  int tid = threadIdx.x, w = tid >> 6, l = tid & 63;
  int lr = l & 15, lg = l >> 4;

  const unsigned short* qb = qkv + (size_t)(b * T_SEQ + r0 + lr) * LDQKV + h * HD + lg * 8;
  bf16x8 qf0 = *(const bf16x8*)(qb);          // Q pre-scaled by 1/8 in qkv epilogue
  bf16x8 qf1 = *(const bf16x8*)(qb + 32);

  // Phase 1 — QK^T: wave w owns key-cols [w*256, w*256+256); K from packed kt panel
  const unsigned short* kb0 = kt + (size_t)bh * T_SEQ * HD + lg * 8;
#pragma unroll
  for (int nt = 0; nt < 16; nt++) {
    int c = w * 256 + nt * 16 + lr;
    const unsigned short* kp = kb0 + (size_t)c * HD;
    bf16x8 kf0 = *(const bf16x8*)(kp);
    bf16x8 kf1 = *(const bf16x8*)(kp + 32);
    f32x4 a = {};
    __builtin_amdgcn_s_setprio(1);
    a = __builtin_amdgcn_mfma_f32_16x16x32_bf16(qf0, kf0, a, 0, 0, 0);
    a = __builtin_amdgcn_mfma_f32_16x16x32_bf16(qf1, kf1, a, 0, 0, 0);
    __builtin_amdgcn_s_setprio(0);
#pragma unroll
    for (int r = 0; r < 4; r++) {
      int row = lg * 4 + r;
      int byteoff = (c * 2) ^ ((row & 7) << 4);
      *(unsigned short*)((char*)S + row * 4096 + byteoff) = f2bf(a[r]);
    }
  }
  __syncthreads();

  // Phase 2 — softmax: wave w rows {2w, 2w+1}; prev coalesced float4
  const float* pvb = prev + ((size_t)bh * T_SEQ + r0 + 2 * w) * T_SEQ;
  float* arow0 = attn_out + ((size_t)bh * T_SEQ + r0 + 2 * w) * T_SEQ;
#pragma unroll
  for (int rr = 0; rr < 2; rr++) {
    int row = w * 2 + rr;
    char* Sr = (char*)S + row * 4096;
    int xv = (row & 7) << 4;
    const float* pr = pvb + (size_t)rr * T_SEQ;
    float* ar = arow0 + (size_t)rr * T_SEQ;
    f32x4 sv[8];
    float mx = -1e30f;
#pragma unroll
    for (int i = 0; i < 8; i++) {
      int c = l * 4 + i * 256;
      ushort4 sraw = *(const ushort4*)(Sr + ((2 * c) ^ xv));
      f32x4 p = *(const f32x4*)(pr + c);
      sv[i][0] = bf2f(sraw.x) + p[0];
      sv[i][1] = bf2f(sraw.y) + p[1];
      sv[i][2] = bf2f(sraw.z) + p[2];
      sv[i][3] = bf2f(sraw.w) + p[3];
      mx = fmaxf(mx, fmaxf(fmaxf(sv[i][0], sv[i][1]), fmaxf(sv[i][2], sv[i][3])));
    }
#pragma unroll
    for (int o = 32; o; o >>= 1) mx = fmaxf(mx, __shfl_xor(mx, o));
    float sum = 0.f;
#pragma unroll
    for (int i = 0; i < 8; i++) {
      sv[i][0] = __expf(sv[i][0] - mx);
      sv[i][1] = __expf(sv[i][1] - mx);
      sv[i][2] = __expf(sv[i][2] - mx);
      sv[i][3] = __expf(sv[i][3] - mx);
      sum += sv[i][0] + sv[i][1] + sv[i][2] + sv[i][3];
    }
#pragma unroll
    for (int o = 32; o; o >>= 1) sum += __shfl_xor(sum, o);
    float inv = 1.0f / sum;
#pragma unroll
    for (int i = 0; i < 8; i++) {
      int c = l * 4 + i * 256;
      f32x4 p4;
      p4[0] = sv[i][0] * inv; p4[1] = sv[i][1] * inv;
      p4[2] = sv[i][2] * inv; p4[3] = sv[i][3] * inv;
      __builtin_nontemporal_store(p4, (f32x4*)(ar + c));
      uint2 pk;
      pk.x = cvtpk(p4[0], p4[1]);
      pk.y = cvtpk(p4[2], p4[3]);
      *(uint2*)(Sr + ((2 * c) ^ xv)) = pk;
    }
  }
  __syncthreads();

  // Phase 3 — PV: wave w key-slice [w*256, +256); A = P (bf16 LDS), B = vt2 tiled
  f32x4 pacc[4] = {};
  const unsigned short* vb = vt2 + (size_t)bh * 64 * HD * 32;
#pragma unroll
  for (int kt_i = 0; kt_i < 8; kt_i++) {
    int kb = w * 256 + kt_i * 32;
    char* Sr = (char*)S + lr * 4096;
    int byteoff = ((kb + lg * 8) * 2) ^ ((lr & 7) << 4);
    bf16x8 af = *(const bf16x8*)(Sr + byteoff);
    const unsigned short* vtile = vb + (size_t)(kb >> 5) * HD * 32;
    __builtin_amdgcn_s_setprio(1);
#pragma unroll
    for (int nj = 0; nj < 4; nj++) {
      const unsigned short* vp = vtile + (size_t)(nj * 16 + lr) * 32 + lg * 8;
      bf16x8 bv = *(const bf16x8*)(vp);
      pacc[nj] = __builtin_amdgcn_mfma_f32_16x16x32_bf16(af, bv, pacc[nj], 0, 0, 0);
    }
    __builtin_amdgcn_s_setprio(0);
  }
  __syncthreads();

  float* P = (float*)S;
#pragma unroll
  for (int nj = 0; nj < 4; nj++)
#pragma unroll
    for (int r = 0; r < 4; r++)
      P[(w * 16 + lg * 4 + r) * 64 + nj * 16 + lr] = pacc[nj][r];
  __syncthreads();
  for (int e = tid; e < 1024; e += 512) {
    float s = 0.f;
#pragma unroll
    for (int ww = 0; ww < 8; ww++) s += P[ww * 1024 + e];
    int row = e >> 6, col = e & 63;
    ctx[(size_t)(b * T_SEQ + r0 + row) * D_MODEL + h * HD + col] = f2bf(s);
  }
}

extern "C" void kernel_launch(void* const* d_in, const int* in_sizes, int n_in,
                              void* d_out, int out_size, void* d_ws, size_t ws_size,
                              hipStream_t stream) {
  const float* x = (const float*)d_in[0];
  const float* prev = (const float*)d_in[1];
  const float* w_qkv = (const float*)d_in[2];
  const float* w_out = (const float*)d_in[3];
  const float* w1 = (const float*)d_in[4];
  const float* b1 = (const float*)d_in[5];
  const float* w2 = (const float*)d_in[6];
  const float* b2 = (const float*)d_in[7];
  const float* g1 = (const float*)d_in[8];
  const float* be1 = (const float*)d_in[9];
  const float* g2 = (const float*)d_in[10];
  const float* be2 = (const float*)d_in[11];
  float* out_x = (float*)d_out;
  float* out_attn = out_x + (size_t)N_ROWS * D_MODEL;

  char* p = (char*)d_ws;
  auto alloc = [&](size_t bytes) -> void* {
    void* r = (void*)p;
    p += (bytes + 255) & ~(size_t)255;
    return r;
  };
  unsigned short* wqkvT = (unsigned short*)alloc((size_t)3072 * 1024 * 2);
  unsigned short* woutT = (unsigned short*)alloc((size_t)1024 * 1024 * 2);
  unsigned short* w1T   = (unsigned short*)alloc((size_t)4096 * 1024 * 2);
  unsigned short* w2T   = (unsigned short*)alloc((size_t)1024 * 4096 * 2);
  unsigned short* ln1b  = (unsigned short*)alloc((size_t)N_ROWS * 1024 * 2);
  unsigned short* qkvb  = (unsigned short*)alloc((size_t)N_ROWS * 3072 * 2);
  unsigned short* ktb   = (unsigned short*)alloc((size_t)32 * 2048 * 64 * 2);
  unsigned short* vt2b  = (unsigned short*)alloc((size_t)32 * 64 * 64 * 32 * 2);
  unsigned short* ctxb  = (unsigned short*)alloc((size_t)N_ROWS * 1024 * 2);
  float*          x2b   = (float*)alloc((size_t)N_ROWS * 1024 * 4);
  unsigned short* ln2b  = (unsigned short*)alloc((size_t)N_ROWS * 1024 * 2);
  unsigned short* hb    = (unsigned short*)alloc((size_t)N_ROWS * 4096 * 2);

  transpose_all<<<12288, 256, 0, stream>>>(w_qkv, w_out, w1, w2, wqkvT, woutT, w1T, w2T);

  ln_kernel<<<N_ROWS, 256, 0, stream>>>(x, g1, be1, ln1b);
  gemm_bt<0><<<dim3(32, 24), 256, 0, stream>>>(ln1b, wqkvT, N_ROWS, 3072, 1024, qkvb, nullptr, ktb, vt2b);
  attn_kernel<<<32 * 128, 512, 0, stream>>>(qkvb, ktb, vt2b, prev, out_attn, ctxb);
  gemm_bt2<1><<<dim3(64, 8), 256, 0, stream>>>(ctxb, woutT, N_ROWS, 1024, 1024, x2b, nullptr, x);
  ln_kernel<<<N_ROWS, 256, 0, stream>>>(x2b, g2, be2, ln2b);
  gemm_bt<2><<<dim3(32, 32), 256, 0, stream>>>(ln2b, w1T, N_ROWS, 4096, 1024, hb, b1, nullptr, nullptr);
  gemm_bt2<3><<<dim3(64, 8), 256, 0, stream>>>(hb, w2T, N_ROWS, 1024, 4096, out_x, b2, x2b);
}